// Round 15
// baseline (370.221 us; speedup 1.0000x reference)
//
#include <hip/hip_runtime.h>
#include <hip/hip_bf16.h>

#define TOK 2048      // B*S
#define DIM 1024      // D
#define HID 4096      // H
#define NE  8         // experts

typedef short bf16x8 __attribute__((ext_vector_type(8)));
typedef float f32x4 __attribute__((ext_vector_type(4)));
typedef unsigned short ushort_t;
typedef unsigned int uint_t;

// XOR-swizzle on 16B slots within a 64B row-payload (rows stride 80B).
#define SWZB(n) (((((n) >> 2) ^ ((n) >> 4)) & 3) << 4)

__device__ __forceinline__ ushort_t f2bf(float f) {
  uint_t b = __float_as_uint(f);
  uint_t r = (b + 0x7FFFu + ((b >> 16) & 1u)) >> 16;
  return (ushort_t)r;
}
__device__ __forceinline__ float bf2f(ushort_t u) {
  return __uint_as_float(((uint_t)u) << 16);
}
// HW packed convert: {bf16(a), bf16(b)} in one VOP3 (RNE, same as f2bf)
__device__ __forceinline__ uint_t pk2bf(float a, float b) {
  uint_t r;
  asm("v_cvt_pk_bf16_f32 %0, %1, %2" : "=v"(r) : "v"(a), "v"(b));
  return r;
}

// ---------------- router (fused: also emits xb = bf16(x)) ----------------
__global__ void router_kernel(const float* __restrict__ x,
                              const float* __restrict__ rw,
                              const float* __restrict__ rb,
                              float* __restrict__ tok_ss,
                              int* __restrict__ top_e,
                              float* __restrict__ top_w,
                              ushort_t* __restrict__ xb) {
  const int t = blockIdx.x;
  const int lane = threadIdx.x;
  float acc[NE];
#pragma unroll
  for (int e = 0; e < NE; ++e) acc[e] = 0.f;
  const float4* x4 = (const float4*)(x + (size_t)t * DIM);
  uint2* xb2 = (uint2*)(xb + (size_t)t * DIM);
#pragma unroll
  for (int j = 0; j < 4; ++j) {
    int i = j * 64 + lane;
    float4 v = x4[i];
    uint2 u;
    u.x = pk2bf(v.x, v.y);
    u.y = pk2bf(v.z, v.w);
    xb2[i] = u;
    const float* w = rw + (size_t)i * 4 * NE;
    const float* vp = (const float*)&v;
#pragma unroll
    for (int c = 0; c < 4; ++c)
#pragma unroll
      for (int e = 0; e < NE; ++e) acc[e] += vp[c] * w[c * NE + e];
  }
#pragma unroll
  for (int e = 0; e < NE; ++e) {
    float v = acc[e];
#pragma unroll
    for (int off = 32; off > 0; off >>= 1) v += __shfl_down(v, off, 64);
    acc[e] = v;
  }
  if (lane == 0) {
    float sc[NE];
    float ss = 0.f;
#pragma unroll
    for (int e = 0; e < NE; ++e) {
      float lg = acc[e] + rb[e];
      ss += lg * lg;
      sc[e] = 1.f / (1.f + expf(-lg));
    }
    tok_ss[t] = ss;
    int i0 = 0;
#pragma unroll
    for (int e = 1; e < NE; ++e) if (sc[e] > sc[i0]) i0 = e;
    int i1 = (i0 == 0) ? 1 : 0;
#pragma unroll
    for (int e = 0; e < NE; ++e) if (e != i0 && sc[e] > sc[i1]) i1 = e;
    float s0 = sc[i0], s1 = sc[i1];
    float inv = 1.f / (s0 + s1 + 1e-6f);
    top_e[t * 2 + 0] = i0;
    top_e[t * 2 + 1] = i1;
    top_w[t * 2 + 0] = s0 * inv;
    top_w[t * 2 + 1] = s1 * inv;
  }
}

// histogram + scan + assign fused: single block, 256 threads
__global__ void scan_assign_kernel(const int* __restrict__ top_e,
                                   const float* __restrict__ top_w,
                                   int* __restrict__ offsets,
                                   int* __restrict__ list_tok,
                                   float* __restrict__ list_w) {
  __shared__ int lcount[NE];
  __shared__ int loff[NE + 1];
  __shared__ int lfill[NE];
  if (threadIdx.x < NE) lcount[threadIdx.x] = 0;
  __syncthreads();
  for (int i = threadIdx.x; i < TOK * 2; i += 256)
    atomicAdd(&lcount[top_e[i]], 1);
  __syncthreads();
  if (threadIdx.x == 0) {
    int o = 0;
    for (int e = 0; e < NE; ++e) { loff[e] = o; lfill[e] = o; o += lcount[e]; }
    loff[NE] = o;
  }
  __syncthreads();
  if (threadIdx.x <= NE) offsets[threadIdx.x] = loff[threadIdx.x];
  for (int i = threadIdx.x; i < TOK * 2; i += 256) {
    int e = top_e[i];
    int idx = atomicAdd(&lfill[e], 1);
    list_tok[idx] = i >> 1;
    list_w[idx] = top_w[i];
  }
}

__global__ void aux_kernel(const float* __restrict__ tok_ss, float* __restrict__ out_aux) {
  __shared__ float sm[256];
  float s = 0.f;
  for (int t = threadIdx.x; t < TOK; t += 256) s += tok_ss[t];
  sm[threadIdx.x] = s;
  __syncthreads();
  for (int w = 128; w > 0; w >>= 1) {
    if (threadIdx.x < w) sm[threadIdx.x] += sm[threadIdx.x + w];
    __syncthreads();
  }
  if (threadIdx.x == 0) *out_aux = 0.01f * sm[0] / (float)(TOK * NE);
}

// ---------------- GEMM1 (r7-proven): h = silu(X@W1)*(X@W2) ----------------
// BM=128 BN=64 BK=32, reg-prefetched staging. B: w12 f32 read directly,
// cvt_pk + transpose to LDS [n][k] (stride 40, SWZB swizzle).
__global__ __launch_bounds__(256)
void gemm1_mfma(const ushort_t* __restrict__ xb,
                const float* __restrict__ w12,
                const int* __restrict__ offsets, const int* __restrict__ list_tok,
                ushort_t* __restrict__ hhi) {
  __shared__ __align__(16) ushort_t Ah[128 * 40];
  __shared__ __align__(16) ushort_t B1[64 * 40];
  __shared__ __align__(16) ushort_t B2[64 * 40];
  __shared__ int stok[128];

  const int e = blockIdx.y >> 4;          // 16 row-tiles of 128 per expert (worst-case 2048 rows)
  const int rt = blockIdx.y & 15;
  const int rowstart = offsets[e] + rt * 128;
  const int rowend = offsets[e + 1];
  if (rowstart >= rowend) return;
  const int h0 = blockIdx.x * 64;
  const int tid = threadIdx.x;
  const int lane = tid & 63, wid = tid >> 6;
  const int wm = wid >> 1, wn = wid & 1;
  const int lr = lane & 15, kh = lane >> 4;

  if (tid < 128) {
    int r = rowstart + tid;
    stok[tid] = list_tok[r < rowend ? r : rowstart];
  }
  __syncthreads();

  f32x4 acc1[4][2], acc2[4][2];
#pragma unroll
  for (int mi = 0; mi < 4; ++mi)
#pragma unroll
    for (int nj = 0; nj < 2; ++nj) {
      acc1[mi][nj] = (f32x4){0.f, 0.f, 0.f, 0.f};
      acc2[mi][nj] = (f32x4){0.f, 0.f, 0.f, 0.f};
    }

  // A staging: 128 rows x 4 seg -> 2 slots/thread
  const int arow0 = tid >> 2, aseg = tid & 3;
  const int arow1 = arow0 + 64;
  const size_t asrc0 = (size_t)stok[arow0] * DIM + aseg * 8;
  const size_t asrc1 = (size_t)stok[arow1] * DIM + aseg * 8;
  const int adst0 = arow0 * 40 + aseg * 8;
  const int adst1 = arow1 * 40 + aseg * 8;

  // B staging ids: p = k-pair (k = 2p,2p+1), n4*4 = col base
  const int p = tid >> 4, n4 = tid & 15;
  const float* w12e = w12 + (size_t)e * DIM * (2 * HID) + h0 + n4 * 4;
  char* B1c = (char*)B1;
  char* B2c = (char*)B2;

  int boff[2];
#pragma unroll
  for (int nj = 0; nj < 2; ++nj) {
    int n = wn * 32 + nj * 16 + lr;
    boff[nj] = n * 80 + ((kh * 16) ^ SWZB(n));
  }
  int bwoff[4];
#pragma unroll
  for (int c = 0; c < 4; ++c) {
    int n = n4 * 4 + c;
    bwoff[c] = n * 80 + ((4 * p) ^ SWZB(n));
  }

  uint4 ra0, ra1;
  float4 w1a, w1b, w2a, w2b;
#define G1_LOAD(K0) do { \
    ra0 = *(const uint4*)&xb[asrc0 + (K0)]; \
    ra1 = *(const uint4*)&xb[asrc1 + (K0)]; \
    const float* r0 = w12e + (size_t)((K0) + 2 * p) * (2 * HID); \
    w1a = *(const float4*)r0; \
    w1b = *(const float4*)(r0 + 2 * HID); \
    w2a = *(const float4*)(r0 + HID); \
    w2b = *(const float4*)(r0 + HID + 2 * HID); \
  } while (0)

  G1_LOAD(0);
#pragma unroll 1
  for (int k0 = 0; k0 < DIM; k0 += 32) {
    *(uint4*)&Ah[adst0] = ra0;
    *(uint4*)&Ah[adst1] = ra1;
    {
      const float* p1a = (const float*)&w1a;
      const float* p1b = (const float*)&w1b;
      const float* p2a = (const float*)&w2a;
      const float* p2b = (const float*)&w2b;
#pragma unroll
      for (int c = 0; c < 4; ++c) {
        *(uint_t*)(B1c + bwoff[c]) = pk2bf(p1a[c], p1b[c]);
        *(uint_t*)(B2c + bwoff[c]) = pk2bf(p2a[c], p2b[c]);
      }
    }
    __syncthreads();
    if (k0 + 32 < DIM) G1_LOAD(k0 + 32);

    bf16x8 af[4], b1f[2], b2f[2];
#pragma unroll
    for (int mi = 0; mi < 4; ++mi)
      af[mi] = *(bf16x8*)&Ah[(wm * 64 + mi * 16 + lr) * 40 + kh * 8];
#pragma unroll
    for (int nj = 0; nj < 2; ++nj) {
      b1f[nj] = *(bf16x8*)(B1c + boff[nj]);
      b2f[nj] = *(bf16x8*)(B2c + boff[nj]);
    }
#pragma unroll
    for (int mi = 0; mi < 4; ++mi)
#pragma unroll
      for (int nj = 0; nj < 2; ++nj) {
        acc1[mi][nj] = __builtin_amdgcn_mfma_f32_16x16x32_bf16(af[mi], b1f[nj], acc1[mi][nj], 0, 0, 0);
        acc2[mi][nj] = __builtin_amdgcn_mfma_f32_16x16x32_bf16(af[mi], b2f[nj], acc2[mi][nj], 0, 0, 0);
      }
    __syncthreads();
  }
#undef G1_LOAD

#pragma unroll
  for (int mi = 0; mi < 4; ++mi)
#pragma unroll
    for (int nj = 0; nj < 2; ++nj)
#pragma unroll
      for (int r = 0; r < 4; ++r) {
        int row_t = wm * 64 + mi * 16 + kh * 4 + r;
        int gr = rowstart + row_t;
        if (gr < rowend) {
          int col = h0 + wn * 32 + nj * 16 + lr;
          float v1 = acc1[mi][nj][r], v2 = acc2[mi][nj][r];
          float hv = (v1 / (1.f + expf(-v1))) * v2;
          hhi[(size_t)gr * HID + col] = f2bf(hv);
        }
      }
}

// ---------------- GEMM2: out += w * (h @ W3) (atomic combine) ----------------
// NEW shape = gemm1's proven BM=128 BN=64 BK=32, single B matrix.
// acc[4][2] = 32 AGPR; ~70 VGPR -> ~5 waves/SIMD. Reg-prefetched staging,
// cvt_pk B-stage, atomic combine epilogue. Grid y = NE*16 row-tiles of 128.
__global__ __launch_bounds__(256)
void gemm2_mfma(const ushort_t* __restrict__ hhi,
                const float* __restrict__ w3,
                const int* __restrict__ offsets, const float* __restrict__ list_w,
                const int* __restrict__ list_tok,
                float* __restrict__ out) {
  __shared__ __align__(16) ushort_t As[128 * 40];
  __shared__ __align__(16) ushort_t Bs[64 * 40];

  const int e = blockIdx.y >> 4;          // 16 row-tiles of 128 per expert
  const int rt = blockIdx.y & 15;
  const int rowstart = offsets[e] + rt * 128;
  const int rowend = offsets[e + 1];
  if (rowstart >= rowend) return;
  const int d0 = blockIdx.x * 64;
  const int tid = threadIdx.x;
  const int lane = tid & 63, wid = tid >> 6;
  const int wm = wid >> 1, wn = wid & 1;
  const int lr = lane & 15, kh = lane >> 4;

  f32x4 acc[4][2];
#pragma unroll
  for (int mi = 0; mi < 4; ++mi)
#pragma unroll
    for (int nj = 0; nj < 2; ++nj) acc[mi][nj] = (f32x4){0.f, 0.f, 0.f, 0.f};

  // A staging: 128 rows x 4 seg -> 2 slots/thread (rows contiguous in hhi)
  const int arow0 = tid >> 2, aseg = tid & 3;
  const int arow1 = arow0 + 64;
  int gr0 = rowstart + arow0; if (gr0 >= rowend) gr0 = rowstart;
  int gr1 = rowstart + arow1; if (gr1 >= rowend) gr1 = rowstart;
  const size_t asrc0 = (size_t)gr0 * HID + aseg * 8;
  const size_t asrc1 = (size_t)gr1 * HID + aseg * 8;
  const int adst0 = arow0 * 40 + aseg * 8;
  const int adst1 = arow1 * 40 + aseg * 8;

  // B staging ids: p = k-pair (k = 2p,2p+1), n4*4 = col base
  const int p = tid >> 4, n4 = tid & 15;
  const float* w3e = w3 + (size_t)e * HID * DIM + d0 + n4 * 4;
  char* Bsc = (char*)Bs;

  int boff[2];
#pragma unroll
  for (int nj = 0; nj < 2; ++nj) {
    int n = wn * 32 + nj * 16 + lr;
    boff[nj] = n * 80 + ((kh * 16) ^ SWZB(n));
  }
  int bwoff[4];
#pragma unroll
  for (int c = 0; c < 4; ++c) {
    int n = n4 * 4 + c;
    bwoff[c] = n * 80 + ((4 * p) ^ SWZB(n));
  }

  uint4 ra0, ra1;
  float4 rb0, rb1;
#define G2_LOAD(K0) do { \
    ra0 = *(const uint4*)&hhi[asrc0 + (K0)]; \
    ra1 = *(const uint4*)&hhi[asrc1 + (K0)]; \
    const float* r0 = w3e + (size_t)((K0) + 2 * p) * DIM; \
    rb0 = *(const float4*)r0; \
    rb1 = *(const float4*)(r0 + DIM); \
  } while (0)

  G2_LOAD(0);
#pragma unroll 1
  for (int k0 = 0; k0 < HID; k0 += 32) {
    *(uint4*)&As[adst0] = ra0;
    *(uint4*)&As[adst1] = ra1;
    {
      const float* pv0 = (const float*)&rb0;
      const float* pv1 = (const float*)&rb1;
#pragma unroll
      for (int c = 0; c < 4; ++c)
        *(uint_t*)(Bsc + bwoff[c]) = pk2bf(pv0[c], pv1[c]);
    }
    __syncthreads();
    if (k0 + 32 < HID) G2_LOAD(k0 + 32);

    bf16x8 af[4], bf[2];
#pragma unroll
    for (int mi = 0; mi < 4; ++mi)
      af[mi] = *(bf16x8*)&As[(wm * 64 + mi * 16 + lr) * 40 + kh * 8];
#pragma unroll
    for (int nj = 0; nj < 2; ++nj)
      bf[nj] = *(bf16x8*)(Bsc + boff[nj]);
#pragma unroll
    for (int mi = 0; mi < 4; ++mi)
#pragma unroll
      for (int nj = 0; nj < 2; ++nj)
        acc[mi][nj] = __builtin_amdgcn_mfma_f32_16x16x32_bf16(af[mi], bf[nj], acc[mi][nj], 0, 0, 0);
    __syncthreads();
  }
#undef G2_LOAD

  // epilogue: out[token, col] += w * acc   (2 contributions/element, commutative)
#pragma unroll
  for (int mi = 0; mi < 4; ++mi)
#pragma unroll
    for (int nj = 0; nj < 2; ++nj)
#pragma unroll
      for (int r = 0; r < 4; ++r) {
        int grr = rowstart + wm * 64 + mi * 16 + kh * 4 + r;
        if (grr < rowend) {
          int col = d0 + wn * 32 + nj * 16 + lr;
          int tok = list_tok[grr];
          atomicAdd(&out[(size_t)tok * DIM + col], acc[mi][nj][r] * list_w[grr]);
        }
      }
}

extern "C" void kernel_launch(void* const* d_in, const int* in_sizes, int n_in,
                              void* d_out, int out_size, void* d_ws, size_t ws_size,
                              hipStream_t stream) {
  const float* x   = (const float*)d_in[0];
  const float* rw  = (const float*)d_in[1];
  const float* rb  = (const float*)d_in[2];
  const float* w12 = (const float*)d_in[3];
  const float* w3  = (const float*)d_in[4];
  float* out = (float*)d_out;

  char* ws = (char*)d_ws;
  size_t off = 0;
  auto alloc = [&](size_t bytes) {
    void* p = ws + off;
    off = (off + bytes + 255) & ~255ULL;
    return p;
  };
  int*   offsets  = (int*)alloc((NE + 1) * 4);
  float* tok_ss   = (float*)alloc(TOK * 4);
  int*   top_e    = (int*)alloc(TOK * 2 * 4);
  float* top_w    = (float*)alloc(TOK * 2 * 4);
  int*   list_tok = (int*)alloc(TOK * 2 * 4);
  float* list_w   = (float*)alloc(TOK * 2 * 4);

  ushort_t* xb  = (ushort_t*)alloc((size_t)TOK * DIM * 2);        // 4 MB
  ushort_t* hhi = (ushort_t*)alloc((size_t)TOK * 2 * HID * 2);    // 32 MB

  // zero the main output (aux slot written by aux_kernel separately)
  hipMemsetAsync(out, 0, (size_t)TOK * DIM * 4, stream);

  hipLaunchKernelGGL(router_kernel, dim3(TOK), dim3(64), 0, stream,
                     x, rw, rb, tok_ss, top_e, top_w, xb);
  hipLaunchKernelGGL(scan_assign_kernel, dim3(1), dim3(256), 0, stream,
                     top_e, top_w, offsets, list_tok, list_w);
  hipLaunchKernelGGL(aux_kernel, dim3(1), dim3(256), 0, stream,
                     tok_ss, out + (size_t)TOK * DIM);

  hipLaunchKernelGGL(gemm1_mfma, dim3(HID / 64, NE * 16), dim3(256), 0, stream,
                     xb, w12, offsets, list_tok, hhi);
  hipLaunchKernelGGL(gemm2_mfma, dim3(DIM / 64, NE * 16), dim3(256), 0, stream,
                     hhi, w3, offsets, list_w, list_tok, out);
}

// Round 16
// 300.459 us; speedup vs baseline: 1.2322x; 1.2322x over previous
//
#include <hip/hip_runtime.h>
#include <hip/hip_bf16.h>

#define TOK 2048      // B*S
#define DIM 1024      // D
#define HID 4096      // H
#define NE  8         // experts

typedef short bf16x8 __attribute__((ext_vector_type(8)));
typedef float f32x4 __attribute__((ext_vector_type(4)));
typedef unsigned short ushort_t;
typedef unsigned int uint_t;

// XOR-swizzle on 16B slots within a 64B row-payload (rows stride 80B).
#define SWZB(n) (((((n) >> 2) ^ ((n) >> 4)) & 3) << 4)

__device__ __forceinline__ ushort_t f2bf(float f) {
  uint_t b = __float_as_uint(f);
  uint_t r = (b + 0x7FFFu + ((b >> 16) & 1u)) >> 16;
  return (ushort_t)r;
}
__device__ __forceinline__ float bf2f(ushort_t u) {
  return __uint_as_float(((uint_t)u) << 16);
}
// HW packed convert: {bf16(a), bf16(b)} in one VOP3 (RNE, same as f2bf)
__device__ __forceinline__ uint_t pk2bf(float a, float b) {
  uint_t r;
  asm("v_cvt_pk_bf16_f32 %0, %1, %2" : "=v"(r) : "v"(a), "v"(b));
  return r;
}

// ---------------- router (fused: also emits xb = bf16(x)) ----------------
__global__ void router_kernel(const float* __restrict__ x,
                              const float* __restrict__ rw,
                              const float* __restrict__ rb,
                              float* __restrict__ tok_ss,
                              int* __restrict__ top_e,
                              float* __restrict__ top_w,
                              ushort_t* __restrict__ xb) {
  const int t = blockIdx.x;
  const int lane = threadIdx.x;
  float acc[NE];
#pragma unroll
  for (int e = 0; e < NE; ++e) acc[e] = 0.f;
  const float4* x4 = (const float4*)(x + (size_t)t * DIM);
  uint2* xb2 = (uint2*)(xb + (size_t)t * DIM);
#pragma unroll
  for (int j = 0; j < 4; ++j) {
    int i = j * 64 + lane;
    float4 v = x4[i];
    uint2 u;
    u.x = pk2bf(v.x, v.y);
    u.y = pk2bf(v.z, v.w);
    xb2[i] = u;
    const float* w = rw + (size_t)i * 4 * NE;
    const float* vp = (const float*)&v;
#pragma unroll
    for (int c = 0; c < 4; ++c)
#pragma unroll
      for (int e = 0; e < NE; ++e) acc[e] += vp[c] * w[c * NE + e];
  }
#pragma unroll
  for (int e = 0; e < NE; ++e) {
    float v = acc[e];
#pragma unroll
    for (int off = 32; off > 0; off >>= 1) v += __shfl_down(v, off, 64);
    acc[e] = v;
  }
  if (lane == 0) {
    float sc[NE];
    float ss = 0.f;
#pragma unroll
    for (int e = 0; e < NE; ++e) {
      float lg = acc[e] + rb[e];
      ss += lg * lg;
      sc[e] = 1.f / (1.f + expf(-lg));
    }
    tok_ss[t] = ss;
    int i0 = 0;
#pragma unroll
    for (int e = 1; e < NE; ++e) if (sc[e] > sc[i0]) i0 = e;
    int i1 = (i0 == 0) ? 1 : 0;
#pragma unroll
    for (int e = 0; e < NE; ++e) if (e != i0 && sc[e] > sc[i1]) i1 = e;
    float s0 = sc[i0], s1 = sc[i1];
    float inv = 1.f / (s0 + s1 + 1e-6f);
    top_e[t * 2 + 0] = i0;
    top_e[t * 2 + 1] = i1;
    top_w[t * 2 + 0] = s0 * inv;
    top_w[t * 2 + 1] = s1 * inv;
  }
}

// histogram + scan + assign + aux-loss fused: single block, 256 threads
__global__ void scan_assign_kernel(const int* __restrict__ top_e,
                                   const float* __restrict__ top_w,
                                   const float* __restrict__ tok_ss,
                                   int* __restrict__ offsets,
                                   int* __restrict__ list_tok,
                                   float* __restrict__ list_w,
                                   float* __restrict__ out_aux) {
  __shared__ int lcount[NE];
  __shared__ int loff[NE + 1];
  __shared__ int lfill[NE];
  __shared__ float sm[256];
  if (threadIdx.x < NE) lcount[threadIdx.x] = 0;
  __syncthreads();
  for (int i = threadIdx.x; i < TOK * 2; i += 256)
    atomicAdd(&lcount[top_e[i]], 1);
  __syncthreads();
  if (threadIdx.x == 0) {
    int o = 0;
    for (int e = 0; e < NE; ++e) { loff[e] = o; lfill[e] = o; o += lcount[e]; }
    loff[NE] = o;
  }
  __syncthreads();
  if (threadIdx.x <= NE) offsets[threadIdx.x] = loff[threadIdx.x];
  for (int i = threadIdx.x; i < TOK * 2; i += 256) {
    int e = top_e[i];
    int idx = atomicAdd(&lfill[e], 1);
    list_tok[idx] = i >> 1;
    list_w[idx] = top_w[i];
  }
  // aux loss (fixed-tree reduction over tok_ss)
  float s = 0.f;
  for (int t = threadIdx.x; t < TOK; t += 256) s += tok_ss[t];
  sm[threadIdx.x] = s;
  __syncthreads();
  for (int w = 128; w > 0; w >>= 1) {
    if (threadIdx.x < w) sm[threadIdx.x] += sm[threadIdx.x + w];
    __syncthreads();
  }
  if (threadIdx.x == 0) *out_aux = 0.01f * sm[0] / (float)(TOK * NE);
}

// ---------------- GEMM1 (r7-proven): h = silu(X@W1)*(X@W2) ----------------
// BM=128 BN=64 BK=32, reg-prefetched staging. B: w12 f32 read directly,
// cvt_pk + transpose to LDS [n][k] (stride 40, SWZB swizzle).
__global__ __launch_bounds__(256)
void gemm1_mfma(const ushort_t* __restrict__ xb,
                const float* __restrict__ w12,
                const int* __restrict__ offsets, const int* __restrict__ list_tok,
                ushort_t* __restrict__ hhi) {
  __shared__ __align__(16) ushort_t Ah[128 * 40];
  __shared__ __align__(16) ushort_t B1[64 * 40];
  __shared__ __align__(16) ushort_t B2[64 * 40];
  __shared__ int stok[128];

  const int e = blockIdx.y >> 4;          // 16 row-tiles of 128 per expert (worst-case 2048 rows)
  const int rt = blockIdx.y & 15;
  const int rowstart = offsets[e] + rt * 128;
  const int rowend = offsets[e + 1];
  if (rowstart >= rowend) return;
  const int h0 = blockIdx.x * 64;
  const int tid = threadIdx.x;
  const int lane = tid & 63, wid = tid >> 6;
  const int wm = wid >> 1, wn = wid & 1;
  const int lr = lane & 15, kh = lane >> 4;

  if (tid < 128) {
    int r = rowstart + tid;
    stok[tid] = list_tok[r < rowend ? r : rowstart];
  }
  __syncthreads();

  f32x4 acc1[4][2], acc2[4][2];
#pragma unroll
  for (int mi = 0; mi < 4; ++mi)
#pragma unroll
    for (int nj = 0; nj < 2; ++nj) {
      acc1[mi][nj] = (f32x4){0.f, 0.f, 0.f, 0.f};
      acc2[mi][nj] = (f32x4){0.f, 0.f, 0.f, 0.f};
    }

  // A staging: 128 rows x 4 seg -> 2 slots/thread
  const int arow0 = tid >> 2, aseg = tid & 3;
  const int arow1 = arow0 + 64;
  const size_t asrc0 = (size_t)stok[arow0] * DIM + aseg * 8;
  const size_t asrc1 = (size_t)stok[arow1] * DIM + aseg * 8;
  const int adst0 = arow0 * 40 + aseg * 8;
  const int adst1 = arow1 * 40 + aseg * 8;

  // B staging ids: p = k-pair (k = 2p,2p+1), n4*4 = col base
  const int p = tid >> 4, n4 = tid & 15;
  const float* w12e = w12 + (size_t)e * DIM * (2 * HID) + h0 + n4 * 4;
  char* B1c = (char*)B1;
  char* B2c = (char*)B2;

  int boff[2];
#pragma unroll
  for (int nj = 0; nj < 2; ++nj) {
    int n = wn * 32 + nj * 16 + lr;
    boff[nj] = n * 80 + ((kh * 16) ^ SWZB(n));
  }
  int bwoff[4];
#pragma unroll
  for (int c = 0; c < 4; ++c) {
    int n = n4 * 4 + c;
    bwoff[c] = n * 80 + ((4 * p) ^ SWZB(n));
  }

  uint4 ra0, ra1;
  float4 w1a, w1b, w2a, w2b;
#define G1_LOAD(K0) do { \
    ra0 = *(const uint4*)&xb[asrc0 + (K0)]; \
    ra1 = *(const uint4*)&xb[asrc1 + (K0)]; \
    const float* r0 = w12e + (size_t)((K0) + 2 * p) * (2 * HID); \
    w1a = *(const float4*)r0; \
    w1b = *(const float4*)(r0 + 2 * HID); \
    w2a = *(const float4*)(r0 + HID); \
    w2b = *(const float4*)(r0 + HID + 2 * HID); \
  } while (0)

  G1_LOAD(0);
#pragma unroll 1
  for (int k0 = 0; k0 < DIM; k0 += 32) {
    *(uint4*)&Ah[adst0] = ra0;
    *(uint4*)&Ah[adst1] = ra1;
    {
      const float* p1a = (const float*)&w1a;
      const float* p1b = (const float*)&w1b;
      const float* p2a = (const float*)&w2a;
      const float* p2b = (const float*)&w2b;
#pragma unroll
      for (int c = 0; c < 4; ++c) {
        *(uint_t*)(B1c + bwoff[c]) = pk2bf(p1a[c], p1b[c]);
        *(uint_t*)(B2c + bwoff[c]) = pk2bf(p2a[c], p2b[c]);
      }
    }
    __syncthreads();
    if (k0 + 32 < DIM) G1_LOAD(k0 + 32);

    bf16x8 af[4], b1f[2], b2f[2];
#pragma unroll
    for (int mi = 0; mi < 4; ++mi)
      af[mi] = *(bf16x8*)&Ah[(wm * 64 + mi * 16 + lr) * 40 + kh * 8];
#pragma unroll
    for (int nj = 0; nj < 2; ++nj) {
      b1f[nj] = *(bf16x8*)(B1c + boff[nj]);
      b2f[nj] = *(bf16x8*)(B2c + boff[nj]);
    }
#pragma unroll
    for (int mi = 0; mi < 4; ++mi)
#pragma unroll
      for (int nj = 0; nj < 2; ++nj) {
        acc1[mi][nj] = __builtin_amdgcn_mfma_f32_16x16x32_bf16(af[mi], b1f[nj], acc1[mi][nj], 0, 0, 0);
        acc2[mi][nj] = __builtin_amdgcn_mfma_f32_16x16x32_bf16(af[mi], b2f[nj], acc2[mi][nj], 0, 0, 0);
      }
    __syncthreads();
  }
#undef G1_LOAD

#pragma unroll
  for (int mi = 0; mi < 4; ++mi)
#pragma unroll
    for (int nj = 0; nj < 2; ++nj)
#pragma unroll
      for (int r = 0; r < 4; ++r) {
        int row_t = wm * 64 + mi * 16 + kh * 4 + r;
        int gr = rowstart + row_t;
        if (gr < rowend) {
          int col = h0 + wn * 32 + nj * 16 + lr;
          float v1 = acc1[mi][nj][r], v2 = acc2[mi][nj][r];
          float hv = (v1 / (1.f + expf(-v1))) * v2;
          hhi[(size_t)gr * HID + col] = f2bf(hv);
        }
      }
}

// ---------------- GEMM2 (r10/r14-proven): out += w * (h @ W3) ----------------
// BM=64 BN=64 BK=64 (two 32-k halves), reg prefetch, cvt_pk B-stage,
// atomic combine epilogue. Grid y = NE*32 (worst-case expert skew safe).
__global__ __launch_bounds__(256)
void gemm2_mfma(const ushort_t* __restrict__ hhi,
                const float* __restrict__ w3,
                const int* __restrict__ offsets, const float* __restrict__ list_w,
                const int* __restrict__ list_tok,
                float* __restrict__ out) {
  __shared__ __align__(16) ushort_t As0[64 * 40];
  __shared__ __align__(16) ushort_t As1[64 * 40];
  __shared__ __align__(16) ushort_t Bs0[64 * 40];
  __shared__ __align__(16) ushort_t Bs1[64 * 40];

  const int e = blockIdx.y >> 5;          // 32 row-tiles of 64 per expert
  const int rt = blockIdx.y & 31;
  const int rowstart = offsets[e] + rt * 64;
  const int rowend = offsets[e + 1];
  if (rowstart >= rowend) return;
  const int d0 = blockIdx.x * 64;
  const int tid = threadIdx.x;
  const int lane = tid & 63, wid = tid >> 6;
  const int wm = wid >> 1, wn = wid & 1;
  const int lr = lane & 15, kh = lane >> 4;

  f32x4 acc[2][2];
#pragma unroll
  for (int mi = 0; mi < 2; ++mi)
#pragma unroll
    for (int nj = 0; nj < 2; ++nj) acc[mi][nj] = (f32x4){0.f, 0.f, 0.f, 0.f};

  const int arow = tid >> 2, aseg = tid & 3;
  int gr = rowstart + arow; if (gr >= rowend) gr = rowstart;
  const size_t asrc = (size_t)gr * HID + aseg * 8;
  const int adst = arow * 40 + aseg * 8;

  const int p = tid >> 4, n4 = tid & 15;
  const float* w3e = w3 + (size_t)e * HID * DIM + d0 + n4 * 4;
  char* Bs0c = (char*)Bs0;
  char* Bs1c = (char*)Bs1;

  int boff[2];
#pragma unroll
  for (int nj = 0; nj < 2; ++nj) {
    int n = wn * 32 + nj * 16 + lr;
    boff[nj] = n * 80 + ((kh * 16) ^ SWZB(n));
  }
  int bwoff[4];
#pragma unroll
  for (int c = 0; c < 4; ++c) {
    int n = n4 * 4 + c;
    bwoff[c] = n * 80 + ((4 * p) ^ SWZB(n));
  }

  uint4 ra0, ra1;
  float4 rb00, rb01, rb10, rb11;
#define G2_LOAD(K0) do { \
    ra0 = *(const uint4*)&hhi[asrc + (K0)]; \
    ra1 = *(const uint4*)&hhi[asrc + (K0) + 32]; \
    const float* r0 = w3e + (size_t)((K0) + 2 * p) * DIM; \
    rb00 = *(const float4*)r0; \
    rb01 = *(const float4*)(r0 + DIM); \
    const float* r1 = w3e + (size_t)((K0) + 32 + 2 * p) * DIM; \
    rb10 = *(const float4*)r1; \
    rb11 = *(const float4*)(r1 + DIM); \
  } while (0)

  G2_LOAD(0);
#pragma unroll 1
  for (int k0 = 0; k0 < HID; k0 += 64) {
    *(uint4*)&As0[adst] = ra0;
    *(uint4*)&As1[adst] = ra1;
    {
      const float* pv0 = (const float*)&rb00;
      const float* pv1 = (const float*)&rb01;
      const float* pw0 = (const float*)&rb10;
      const float* pw1 = (const float*)&rb11;
#pragma unroll
      for (int c = 0; c < 4; ++c) {
        *(uint_t*)(Bs0c + bwoff[c]) = pk2bf(pv0[c], pv1[c]);
        *(uint_t*)(Bs1c + bwoff[c]) = pk2bf(pw0[c], pw1[c]);
      }
    }
    __syncthreads();
    if (k0 + 64 < HID) G2_LOAD(k0 + 64);

    // half 0
    {
      bf16x8 af[2], bf[2];
#pragma unroll
      for (int mi = 0; mi < 2; ++mi)
        af[mi] = *(bf16x8*)&As0[(wm * 32 + mi * 16 + lr) * 40 + kh * 8];
#pragma unroll
      for (int nj = 0; nj < 2; ++nj)
        bf[nj] = *(bf16x8*)(Bs0c + boff[nj]);
#pragma unroll
      for (int mi = 0; mi < 2; ++mi)
#pragma unroll
        for (int nj = 0; nj < 2; ++nj)
          acc[mi][nj] = __builtin_amdgcn_mfma_f32_16x16x32_bf16(af[mi], bf[nj], acc[mi][nj], 0, 0, 0);
    }
    // half 1
    {
      bf16x8 af[2], bf[2];
#pragma unroll
      for (int mi = 0; mi < 2; ++mi)
        af[mi] = *(bf16x8*)&As1[(wm * 32 + mi * 16 + lr) * 40 + kh * 8];
#pragma unroll
      for (int nj = 0; nj < 2; ++nj)
        bf[nj] = *(bf16x8*)(Bs1c + boff[nj]);
#pragma unroll
      for (int mi = 0; mi < 2; ++mi)
#pragma unroll
        for (int nj = 0; nj < 2; ++nj)
          acc[mi][nj] = __builtin_amdgcn_mfma_f32_16x16x32_bf16(af[mi], bf[nj], acc[mi][nj], 0, 0, 0);
    }
    __syncthreads();
  }
#undef G2_LOAD

  // epilogue: out[token, col] += w * acc   (2 contributions/element, commutative)
#pragma unroll
  for (int mi = 0; mi < 2; ++mi)
#pragma unroll
    for (int nj = 0; nj < 2; ++nj)
#pragma unroll
      for (int r = 0; r < 4; ++r) {
        int grr = rowstart + wm * 32 + mi * 16 + kh * 4 + r;
        if (grr < rowend) {
          int col = d0 + wn * 32 + nj * 16 + lr;
          int tok = list_tok[grr];
          atomicAdd(&out[(size_t)tok * DIM + col], acc[mi][nj][r] * list_w[grr]);
        }
      }
}

extern "C" void kernel_launch(void* const* d_in, const int* in_sizes, int n_in,
                              void* d_out, int out_size, void* d_ws, size_t ws_size,
                              hipStream_t stream) {
  const float* x   = (const float*)d_in[0];
  const float* rw  = (const float*)d_in[1];
  const float* rb  = (const float*)d_in[2];
  const float* w12 = (const float*)d_in[3];
  const float* w3  = (const float*)d_in[4];
  float* out = (float*)d_out;

  char* ws = (char*)d_ws;
  size_t off = 0;
  auto alloc = [&](size_t bytes) {
    void* p = ws + off;
    off = (off + bytes + 255) & ~255ULL;
    return p;
  };
  int*   offsets  = (int*)alloc((NE + 1) * 4);
  float* tok_ss   = (float*)alloc(TOK * 4);
  int*   top_e    = (int*)alloc(TOK * 2 * 4);
  float* top_w    = (float*)alloc(TOK * 2 * 4);
  int*   list_tok = (int*)alloc(TOK * 2 * 4);
  float* list_w   = (float*)alloc(TOK * 2 * 4);

  ushort_t* xb  = (ushort_t*)alloc((size_t)TOK * DIM * 2);        // 4 MB
  ushort_t* hhi = (ushort_t*)alloc((size_t)TOK * 2 * HID * 2);    // 32 MB

  // zero the main output (aux slot written by scan_assign_kernel)
  hipMemsetAsync(out, 0, (size_t)TOK * DIM * 4, stream);

  hipLaunchKernelGGL(router_kernel, dim3(TOK), dim3(64), 0, stream,
                     x, rw, rb, tok_ss, top_e, top_w, xb);
  hipLaunchKernelGGL(scan_assign_kernel, dim3(1), dim3(256), 0, stream,
                     top_e, top_w, tok_ss, offsets, list_tok, list_w,
                     out + (size_t)TOK * DIM);

  hipLaunchKernelGGL(gemm1_mfma, dim3(HID / 64, NE * 16), dim3(256), 0, stream,
                     xb, w12, offsets, list_tok, hhi);
  hipLaunchKernelGGL(gemm2_mfma, dim3(DIM / 64, NE * 32), dim3(256), 0, stream,
                     hhi, w3, offsets, list_w, list_tok, out);
}